// Round 1
// baseline (9717.915 us; speedup 1.0000x reference)
//
#include <hip/hip_runtime.h>
#include <hip/hip_bf16.h>

// ---------------- problem constants ----------------
#define B_   1024
#define T_   365
#define D_   24
#define H_   128

// bf16 weight arena layout (ushort element offsets)
#define WIH1P_OFF 0         // [384][32]  (24 cols + zero pad)
#define WIH2P_OFF 12288     // [384][32]  (24 x cols, col24 = lai weight, pad)
#define WHH_OFF   24576     // 4 x [384][128]
#define WIH3_OFF  221184    // [384][256]
#define WIH4_OFF  319488    // [384][256]
#define WS_ELEMS  417792

typedef __attribute__((ext_vector_type(8))) short bf16x8;
typedef __attribute__((ext_vector_type(4))) float f32x4;

__device__ __align__(16) unsigned short g_ws[WS_ELEMS];

#define MFMA(a, b, c) __builtin_amdgcn_mfma_f32_16x16x32_bf16((a), (b), (c), 0, 0, 0)
#define WLD(off) (*(const bf16x8*)(g_ws + (off)))

__device__ __forceinline__ unsigned short f2b(float f) {
  union { __hip_bfloat16 h; unsigned short u; } cv;
  cv.h = __float2bfloat16(f);   // RNE
  return cv.u;
}
__device__ __forceinline__ float b2f(unsigned short u) {
  union { float f; unsigned int u32; } cv;
  cv.u32 = ((unsigned int)u) << 16;
  return cv.f;
}
__device__ __forceinline__ float sigmoidf_(float x) { return 1.f / (1.f + __expf(-x)); }
__device__ __forceinline__ float tanhf_(float x) {
  float e = __expf(2.f * x);
  return 1.f - 2.f / (e + 1.f);   // handles +-inf limits correctly
}

// ---------------- prologue: fp32 -> padded bf16 weights ----------------
__global__ void prep_weights(const float* wih1, const float* wih2,
                             const float* whh1, const float* whh2,
                             const float* whh3, const float* whh4,
                             const float* wih3, const float* wih4) {
  int i = blockIdx.x * blockDim.x + threadIdx.x;
  if (i >= WS_ELEMS) return;
  float v;
  if (i < 12288) {                       // Wih1 padded [384][32]
    int r = i >> 5, c = i & 31;
    v = (c < 24) ? wih1[r * 24 + c] : 0.f;
  } else if (i < 24576) {                // Wih2 padded [384][32] (col 24 = lai)
    int j = i - 12288;
    int r = j >> 5, c = j & 31;
    v = (c < 25) ? wih2[r * 25 + c] : 0.f;
  } else if (i < 221184) {               // Whh1..4 [384][128]
    int j = i - 24576;
    if      (j < 49152)  v = whh1[j];
    else if (j < 98304)  v = whh2[j - 49152];
    else if (j < 147456) v = whh3[j - 98304];
    else                 v = whh4[j - 147456];
  } else if (i < 319488) {               // Wih3 [384][256]
    v = wih3[i - 221184];
  } else {                               // Wih4 [384][256]
    v = wih4[i - 319488];
  }
  g_ws[i] = f2b(v);
}

// ---------------- main persistent kernel ----------------
struct GruParams {
  const float* x;
  const float* bih[4];
  const float* bhh[4];
  const float* wfc[4];
  const float* bfc[4];
  float* out;        // [B][T][9]
  float* hf[4];      // [B][128] final states
  float* hT[4];      // [B][T][128]
};

__global__ __launch_bounds__(512, 2) void gru_main(GruParams p) {
  // hfrag[buf][cell][kg][m][e] : bf16 h, chunk (kg,m) = 8 contiguous k for MFMA frags
  __shared__ unsigned short hfrag[2][4][16][16][8];   // 32 KB
  __shared__ unsigned short xa[4][16][8];             // [kg][m][e], 1 KB
  __shared__ float lai_s[16];

  const int tid  = threadIdx.x;
  const int lane = tid & 63;
  const int wid  = tid >> 6;       // 0..7
  const int nlo  = lane & 15;
  const int khi  = lane >> 4;      // 0..3
  const int j0   = wid * 16;
  const int nh   = j0 + nlo;       // hidden column this lane owns
  const int b0   = blockIdx.x * 16;

  for (int i = tid; i < 2 * 4 * 16 * 16 * 8; i += 512) ((unsigned short*)hfrag)[i] = 0;
  if (tid < 16) lai_s[tid] = 0.f;

  // fp32 hidden-state carry lives in registers of the owner thread:
  // hreg[c][q] == h_c[m = khi*4+q][nh]
  float hreg[4][4];
#pragma unroll
  for (int c = 0; c < 4; ++c)
#pragma unroll
    for (int q = 0; q < 4; ++q) hreg[c][q] = 0.f;

  // hoisted biases (r,z combined; n-gate input/hidden kept separate)
  float brz[4][2], bin[4], bhn[4];
#pragma unroll
  for (int c = 0; c < 4; ++c) {
    brz[c][0] = p.bih[c][nh] + p.bhh[c][nh];
    brz[c][1] = p.bih[c][128 + nh] + p.bhh[c][128 + nh];
    bin[c]    = p.bih[c][256 + nh];
    bhn[c]    = p.bhh[c][256 + nh];
  }

  // hoisted weight-fragment offsets (ushort units); g: 0=r,1=z,2=n tile
  unsigned int o_wih1[3], o_wih2[3], o_whh[4][3], o_wih3[3], o_wih4[3];
#pragma unroll
  for (int g = 0; g < 3; ++g) {
    int row = g * 128 + nh;
    o_wih1[g] = WIH1P_OFF + row * 32 + khi * 8;
    o_wih2[g] = WIH2P_OFF + row * 32 + khi * 8;
#pragma unroll
    for (int c = 0; c < 4; ++c) o_whh[c][g] = WHH_OFF + c * 49152 + row * 128 + khi * 8;
    o_wih3[g] = WIH3_OFF + row * 256 + khi * 8;
    o_wih4[g] = WIH4_OFF + row * 256 + khi * 8;
  }

  // hoisted FC assignment: 144 threads = 16 rows x 9 outputs
  const bool fc_on = (tid < 144);
  const int foi = tid % 9;
  int frow = 0, fcell = 0;
  const float4* fw4 = nullptr;
  float fb = 0.f;
  if (fc_on) {
    frow = tid / 9;
    const float* fw;
    if (foi == 0)     { fcell = 0; fw = p.wfc[0];                  fb = p.bfc[0][0]; }
    else if (foi < 4) { fcell = 1; fw = p.wfc[1] + (foi - 1) * 128; fb = p.bfc[1][foi - 1]; }
    else if (foi < 7) { fcell = 2; fw = p.wfc[2] + (foi - 4) * 128; fb = p.bfc[2][foi - 4]; }
    else              { fcell = 3; fw = p.wfc[3] + (foi - 7) * 128; fb = p.bfc[3][foi - 7]; }
    fw4 = (const float4*)fw;
  }

  const int xrow = tid >> 5;   // 0..15
  const int xcol = tid & 31;   // 0..31

  __syncthreads();

  for (int t = 0; t < T_; ++t) {
    // ---- phase 0: stage x_t (+ lai at k=24) into xa fragments ----
    {
      float v;
      if (xcol < 24)       v = p.x[(size_t)(b0 + xrow) * (T_ * D_) + t * D_ + xcol];
      else if (xcol == 24) v = lai_s[xrow];
      else                 v = 0.f;
      xa[xcol >> 3][xrow][xcol & 7] = f2b(v);
    }
    __syncthreads();

    const int ib = t & 1, ob = ib ^ 1;   // old / new hfrag buffers

    // ---- stage A: cells 1 and 2 ----
    {
      bf16x8 ax = *(const bf16x8*)&xa[khi][nlo][0];
      bf16x8 a1[4], a2[4];
#pragma unroll
      for (int kc = 0; kc < 4; ++kc) {
        a1[kc] = *(const bf16x8*)&hfrag[ib][0][kc * 4 + khi][nlo][0];
        a2[kc] = *(const bf16x8*)&hfrag[ib][1][kc * 4 + khi][nlo][0];
      }
      f32x4 R1 = {0.f,0.f,0.f,0.f}, Z1 = R1, I1 = R1, Hh1 = R1;
      f32x4 R2 = R1, Z2 = R1, I2 = R1, Hh2 = R1;
      R1 = MFMA(ax, WLD(o_wih1[0]), R1);
      Z1 = MFMA(ax, WLD(o_wih1[1]), Z1);
      I1 = MFMA(ax, WLD(o_wih1[2]), I1);
      R2 = MFMA(ax, WLD(o_wih2[0]), R2);
      Z2 = MFMA(ax, WLD(o_wih2[1]), Z2);
      I2 = MFMA(ax, WLD(o_wih2[2]), I2);
#pragma unroll
      for (int kc = 0; kc < 4; ++kc) {
        unsigned int ko = kc * 32;
        R1  = MFMA(a1[kc], WLD(o_whh[0][0] + ko), R1);
        Z1  = MFMA(a1[kc], WLD(o_whh[0][1] + ko), Z1);
        Hh1 = MFMA(a1[kc], WLD(o_whh[0][2] + ko), Hh1);
        R2  = MFMA(a2[kc], WLD(o_whh[1][0] + ko), R2);
        Z2  = MFMA(a2[kc], WLD(o_whh[1][1] + ko), Z2);
        Hh2 = MFMA(a2[kc], WLD(o_whh[1][2] + ko), Hh2);
      }
#pragma unroll
      for (int q = 0; q < 4; ++q) {
        int m = khi * 4 + q;
        {
          float r = sigmoidf_(R1[q] + brz[0][0]);
          float z = sigmoidf_(Z1[q] + brz[0][1]);
          float n = tanhf_(I1[q] + bin[0] + r * (Hh1[q] + bhn[0]));
          float hnew = (1.f - z) * n + z * hreg[0][q];
          hreg[0][q] = hnew;
          hfrag[ob][0][nh >> 3][m][nh & 7] = f2b(hnew);
          p.hT[0][(size_t)(b0 + m) * (T_ * H_) + (size_t)t * H_ + nh] = hnew;
        }
        {
          float r = sigmoidf_(R2[q] + brz[1][0]);
          float z = sigmoidf_(Z2[q] + brz[1][1]);
          float n = tanhf_(I2[q] + bin[1] + r * (Hh2[q] + bhn[1]));
          float hnew = (1.f - z) * n + z * hreg[1][q];
          hreg[1][q] = hnew;
          hfrag[ob][1][nh >> 3][m][nh & 7] = f2b(hnew);
          p.hT[1][(size_t)(b0 + m) * (T_ * H_) + (size_t)t * H_ + nh] = hnew;
        }
      }
    }
    __syncthreads();

    // ---- stage B: cell 3, input [h1_new, h2_new], hidden h3_old ----
    bf16x8 h1n[4];   // kept live for stage C
    {
      bf16x8 h2n[4], a3[4];
#pragma unroll
      for (int kc = 0; kc < 4; ++kc) {
        h1n[kc] = *(const bf16x8*)&hfrag[ob][0][kc * 4 + khi][nlo][0];
        h2n[kc] = *(const bf16x8*)&hfrag[ob][1][kc * 4 + khi][nlo][0];
        a3[kc]  = *(const bf16x8*)&hfrag[ib][2][kc * 4 + khi][nlo][0];
      }
      f32x4 R = {0.f,0.f,0.f,0.f}, Z = R, I = R, Hh = R;
#pragma unroll
      for (int kc = 0; kc < 4; ++kc) {
        unsigned int ko = kc * 32;
        R = MFMA(h1n[kc], WLD(o_wih3[0] + ko), R);
        Z = MFMA(h1n[kc], WLD(o_wih3[1] + ko), Z);
        I = MFMA(h1n[kc], WLD(o_wih3[2] + ko), I);
      }
#pragma unroll
      for (int kc = 0; kc < 4; ++kc) {
        unsigned int ko = 128 + kc * 32;
        R = MFMA(h2n[kc], WLD(o_wih3[0] + ko), R);
        Z = MFMA(h2n[kc], WLD(o_wih3[1] + ko), Z);
        I = MFMA(h2n[kc], WLD(o_wih3[2] + ko), I);
      }
#pragma unroll
      for (int kc = 0; kc < 4; ++kc) {
        unsigned int ko = kc * 32;
        R  = MFMA(a3[kc], WLD(o_whh[2][0] + ko), R);
        Z  = MFMA(a3[kc], WLD(o_whh[2][1] + ko), Z);
        Hh = MFMA(a3[kc], WLD(o_whh[2][2] + ko), Hh);
      }
#pragma unroll
      for (int q = 0; q < 4; ++q) {
        int m = khi * 4 + q;
        float r = sigmoidf_(R[q] + brz[2][0]);
        float z = sigmoidf_(Z[q] + brz[2][1]);
        float n = tanhf_(I[q] + bin[2] + r * (Hh[q] + bhn[2]));
        float hnew = (1.f - z) * n + z * hreg[2][q];
        hreg[2][q] = hnew;
        hfrag[ob][2][nh >> 3][m][nh & 7] = f2b(hnew);
        p.hT[2][(size_t)(b0 + m) * (T_ * H_) + (size_t)t * H_ + nh] = hnew;
      }
    }
    __syncthreads();

    // ---- stage C: cell 4, input [h1_new, h3_new], hidden h4_old ----
    {
      bf16x8 h3n[4], a4[4];
#pragma unroll
      for (int kc = 0; kc < 4; ++kc) {
        h3n[kc] = *(const bf16x8*)&hfrag[ob][2][kc * 4 + khi][nlo][0];
        a4[kc]  = *(const bf16x8*)&hfrag[ib][3][kc * 4 + khi][nlo][0];
      }
      f32x4 R = {0.f,0.f,0.f,0.f}, Z = R, I = R, Hh = R;
#pragma unroll
      for (int kc = 0; kc < 4; ++kc) {
        unsigned int ko = kc * 32;
        R = MFMA(h1n[kc], WLD(o_wih4[0] + ko), R);
        Z = MFMA(h1n[kc], WLD(o_wih4[1] + ko), Z);
        I = MFMA(h1n[kc], WLD(o_wih4[2] + ko), I);
      }
#pragma unroll
      for (int kc = 0; kc < 4; ++kc) {
        unsigned int ko = 128 + kc * 32;
        R = MFMA(h3n[kc], WLD(o_wih4[0] + ko), R);
        Z = MFMA(h3n[kc], WLD(o_wih4[1] + ko), Z);
        I = MFMA(h3n[kc], WLD(o_wih4[2] + ko), I);
      }
#pragma unroll
      for (int kc = 0; kc < 4; ++kc) {
        unsigned int ko = kc * 32;
        R  = MFMA(a4[kc], WLD(o_whh[3][0] + ko), R);
        Z  = MFMA(a4[kc], WLD(o_whh[3][1] + ko), Z);
        Hh = MFMA(a4[kc], WLD(o_whh[3][2] + ko), Hh);
      }
#pragma unroll
      for (int q = 0; q < 4; ++q) {
        int m = khi * 4 + q;
        float r = sigmoidf_(R[q] + brz[3][0]);
        float z = sigmoidf_(Z[q] + brz[3][1]);
        float n = tanhf_(I[q] + bin[3] + r * (Hh[q] + bhn[3]));
        float hnew = (1.f - z) * n + z * hreg[3][q];
        hreg[3][q] = hnew;
        hfrag[ob][3][nh >> 3][m][nh & 7] = f2b(hnew);
        p.hT[3][(size_t)(b0 + m) * (T_ * H_) + (size_t)t * H_ + nh] = hnew;
      }
    }
    __syncthreads();

    // ---- FC heads: o1(1), o2(3), o3(3), o4(2); o4[:,0] -> lai ----
    if (fc_on) {
      const unsigned short* hb = &hfrag[ob][fcell][0][frow][0];
      float acc = fb;
#pragma unroll
      for (int kg = 0; kg < 16; ++kg) {
        bf16x8 hv = *(const bf16x8*)(hb + kg * 128);
        float4 wA = fw4[kg * 2], wB = fw4[kg * 2 + 1];
        acc += b2f((unsigned short)hv[0]) * wA.x + b2f((unsigned short)hv[1]) * wA.y +
               b2f((unsigned short)hv[2]) * wA.z + b2f((unsigned short)hv[3]) * wA.w +
               b2f((unsigned short)hv[4]) * wB.x + b2f((unsigned short)hv[5]) * wB.y +
               b2f((unsigned short)hv[6]) * wB.z + b2f((unsigned short)hv[7]) * wB.w;
      }
      p.out[(size_t)(b0 + frow) * (T_ * 9) + t * 9 + foi] = acc;
      if (foi == 7) lai_s[frow] = acc;   // o4 column 0
    }
    __syncthreads();
  }

  // ---- final hidden states (fp32 from register carry) ----
#pragma unroll
  for (int c = 0; c < 4; ++c)
#pragma unroll
    for (int q = 0; q < 4; ++q)
      p.hf[c][(size_t)(b0 + khi * 4 + q) * H_ + nh] = hreg[c][q];
}

// ---------------- launcher ----------------
extern "C" void kernel_launch(void* const* d_in, const int* in_sizes, int n_in,
                              void* d_out, int out_size, void* d_ws, size_t ws_size,
                              hipStream_t stream) {
  (void)in_sizes; (void)n_in; (void)d_ws; (void)ws_size;
  // d_in order: x, then per cell c: Wih, Whh, bih, bhh, Wfc, bfc
  const float* x    = (const float*)d_in[0];
  const float* wih1 = (const float*)d_in[1];
  const float* whh1 = (const float*)d_in[2];
  const float* wih2 = (const float*)d_in[7];
  const float* whh2 = (const float*)d_in[8];
  const float* wih3 = (const float*)d_in[13];
  const float* whh3 = (const float*)d_in[14];
  const float* wih4 = (const float*)d_in[19];
  const float* whh4 = (const float*)d_in[20];

  prep_weights<<<(WS_ELEMS + 255) / 256, 256, 0, stream>>>(wih1, wih2, whh1, whh2,
                                                           whh3, whh4, wih3, wih4);

  GruParams p;
  p.x = x;
  for (int c = 0; c < 4; ++c) {
    p.bih[c] = (const float*)d_in[3 + 6 * c];
    p.bhh[c] = (const float*)d_in[4 + 6 * c];
    p.wfc[c] = (const float*)d_in[5 + 6 * c];
    p.bfc[c] = (const float*)d_in[6 + 6 * c];
  }
  float* out = (float*)d_out;
  p.out = out;                                  // B*T*9 = 3,363,840
  const size_t HF_OFF = (size_t)B_ * T_ * 9;    // 3,363,840
  const size_t HT_OFF = HF_OFF + 4ull * B_ * H_;  // 3,888,128
  const size_t HT_SZ  = (size_t)B_ * T_ * H_;   // 47,841,280
  for (int c = 0; c < 4; ++c) {
    p.hf[c] = out + HF_OFF + (size_t)c * B_ * H_;
    p.hT[c] = out + HT_OFF + (size_t)c * HT_SZ;
  }
  gru_main<<<64, 512, 0, stream>>>(p);
}